// Round 1
// baseline (294.202 us; speedup 1.0000x reference)
//
#include <hip/hip_runtime.h>
#include <stdint.h>

typedef __attribute__((ext_vector_type(8))) __bf16 bf16x8;
typedef __attribute__((ext_vector_type(4))) float f32x4;
typedef __attribute__((ext_vector_type(4))) float fl4;
typedef __attribute__((ext_vector_type(8))) unsigned short us8;
typedef __attribute__((ext_vector_type(4))) unsigned short us4;

__device__ __forceinline__ unsigned short f2bf(float f) {
  union { float f; unsigned int u; } v;
  v.f = f;
  unsigned int r = v.u + 0x7FFFu + ((v.u >> 16) & 1u);
  return (unsigned short)(r >> 16);
}

#define GLOAD_LDS16(g, l)                                                   \
  __builtin_amdgcn_global_load_lds(                                         \
      (__attribute__((address_space(1))) void*)(g),                         \
      (__attribute__((address_space(3))) void*)(l), 16, 0, 0)

// ---------------- fp32 -> bf16 conversion ----------------
__global__ void f32_to_bf16_kernel(const float* __restrict__ in,
                                   unsigned short* __restrict__ out, int n) {
  int i = (blockIdx.x * blockDim.x + threadIdx.x) * 4;
  if (i + 3 < n) {
    fl4 v = *(const fl4*)(in + i);
    us4 o;
    o[0] = f2bf(v[0]);
    o[1] = f2bf(v[1]);
    o[2] = f2bf(v[2]);
    o[3] = f2bf(v[3]);
    *(us4*)(out + i) = o;
  }
}

// ---------------- bf16 NT GEMM: C = A(MxK) * B(NxK)^T + bias ----------------
// A, B row-major K-contiguous bf16. 128x128 tile, BK=64, 4 waves (2x2), each
// wave owns a 64x64 sub-tile (4x4 fragments of 16x16), mfma_f32_16x16x32_bf16.
template <bool OUT_BF16>
__global__ __launch_bounds__(256, 2) void gemm_nt_kernel(
    const unsigned short* __restrict__ A, const unsigned short* __restrict__ B,
    const float* __restrict__ bias, void* __restrict__ Cout, int M, int N,
    int K) {
  __shared__ __align__(16) unsigned short lA[128 * 64];
  __shared__ __align__(16) unsigned short lB[128 * 64];

  const int tid = threadIdx.x;
  const int lane = tid & 63;
  const int wid = tid >> 6;
  const int wr = (wid >> 1) * 64;  // wave row offset in tile
  const int wc = (wid & 1) * 64;   // wave col offset in tile
  const int bm = blockIdx.x * 128;
  const int bn = blockIdx.y * 128;

  const f32x4 zero4 = {0.f, 0.f, 0.f, 0.f};
  f32x4 acc[4][4];
#pragma unroll
  for (int m = 0; m < 4; ++m)
#pragma unroll
    for (int n = 0; n < 4; ++n) acc[m][n] = zero4;

  // staging map: thread t stages 16B chunks; row = (t>>3)+i*32, col8 = (t&7)*8
  const int srow = tid >> 3;
  const int scol = (tid & 7) << 3;
  unsigned short* Ab = (unsigned short*)(A + (size_t)(bm + srow) * K + scol);
  unsigned short* Bb = (unsigned short*)(B + (size_t)(bn + srow) * K + scol);
  unsigned short* lAb = lA + srow * 64 + scol;
  unsigned short* lBb = lB + srow * 64 + scol;

  const int lr = lane & 15;
  const int lk8 = (lane >> 4) * 8;

  const int nkt = K >> 6;
  for (int kt = 0; kt < nkt; ++kt) {
#pragma unroll
    for (int i = 0; i < 4; ++i) {
      GLOAD_LDS16(Ab + (size_t)(i * 32) * K + kt * 64, lAb + i * 32 * 64);
      GLOAD_LDS16(Bb + (size_t)(i * 32) * K + kt * 64, lBb + i * 32 * 64);
    }
    asm volatile("s_waitcnt vmcnt(0)" ::: "memory");
    __syncthreads();
#pragma unroll
    for (int kk = 0; kk < 2; ++kk) {
      bf16x8 af[4], bfr[4];
#pragma unroll
      for (int m = 0; m < 4; ++m)
        af[m] = *(const bf16x8*)(lA + (wr + m * 16 + lr) * 64 + kk * 32 + lk8);
#pragma unroll
      for (int n = 0; n < 4; ++n)
        bfr[n] = *(const bf16x8*)(lB + (wc + n * 16 + lr) * 64 + kk * 32 + lk8);
#pragma unroll
      for (int m = 0; m < 4; ++m)
#pragma unroll
        for (int n = 0; n < 4; ++n)
          acc[m][n] = __builtin_amdgcn_mfma_f32_16x16x32_bf16(af[m], bfr[n],
                                                              acc[m][n], 0, 0, 0);
    }
    __syncthreads();
  }

  // epilogue: C/D layout col = lane&15, row = (lane>>4)*4 + j
  const int crow0 = bm + wr + (lane >> 4) * 4;
  const int ccol0 = bn + wc + lr;
#pragma unroll
  for (int n = 0; n < 4; ++n) {
    const int col = ccol0 + n * 16;
    const float bv = bias[col];
#pragma unroll
    for (int m = 0; m < 4; ++m) {
#pragma unroll
      for (int j = 0; j < 4; ++j) {
        const int row = crow0 + m * 16 + j;
        const float val = acc[m][n][j] + bv;
        if (OUT_BF16)
          ((unsigned short*)Cout)[(size_t)row * N + col] = f2bf(val);
        else
          ((float*)Cout)[(size_t)row * N + col] = val;
      }
    }
  }
}

// ---------------- attention: one WG (4 waves) per (b, h) ----------------
// qkv: (32768 x 1536) bf16 rows = b*64+n, cols = which*512 + h*32 + d
// out: (32768 x 512) bf16 rows = b*64+n, cols = h*32 + d
__global__ __launch_bounds__(256, 2) void attn_kernel(
    const unsigned short* __restrict__ qkv, const float* __restrict__ abias,
    const float* __restrict__ mask, unsigned short* __restrict__ out) {
  __shared__ __align__(16) unsigned short lq[64 * 40];
  __shared__ __align__(16) unsigned short lk[64 * 40];
  __shared__ __align__(16) unsigned short lvT[32 * 72];
  __shared__ __align__(16) float ls[64 * 68];
  __shared__ __align__(16) unsigned short lp[64 * 72];

  const int blk = blockIdx.x;
  const int b = blk >> 4;
  const int h = blk & 15;
  const int tid = threadIdx.x;
  const int lane = tid & 63;
  const int wid = tid >> 6;
  const int lr = lane & 15;
  const int lk8 = (lane >> 4) * 8;

  // ---- stage q, k (row-major, padded stride 40) and v transposed (32x64, stride 72)
  {
    const int r = tid >> 2;           // 0..63
    const int d0 = (tid & 3) * 8;     // 0,8,16,24
    const size_t base = (size_t)(b * 64 + r) * 1536 + h * 32 + d0;
    us8 qv = *(const us8*)(qkv + base);
    us8 kv = *(const us8*)(qkv + base + 512);
    us8 vv = *(const us8*)(qkv + base + 1024);
    *(us8*)(lq + r * 40 + d0) = qv;
    *(us8*)(lk + r * 40 + d0) = kv;
#pragma unroll
    for (int i = 0; i < 8; ++i) lvT[(d0 + i) * 72 + r] = vv[i];
  }
  __syncthreads();

  // ---- S = q @ k^T : wave wid owns rows wid*16..+15, 4 col tiles, K=32
  f32x4 s[4];
  {
    bf16x8 aq = *(const bf16x8*)(lq + (wid * 16 + lr) * 40 + lk8);
#pragma unroll
    for (int n = 0; n < 4; ++n) {
      bf16x8 bk = *(const bf16x8*)(lk + (n * 16 + lr) * 40 + lk8);
      f32x4 z = {0.f, 0.f, 0.f, 0.f};
      s[n] = __builtin_amdgcn_mfma_f32_16x16x32_bf16(aq, bk, z, 0, 0, 0);
    }
  }
  const float scale = 0.17677669529663687f;  // 32^-0.5
  const int sr0 = wid * 16 + (lane >> 4) * 4;
#pragma unroll
  for (int n = 0; n < 4; ++n) {
    const int col = n * 16 + lr;
#pragma unroll
    for (int j = 0; j < 4; ++j) {
      const int row = sr0 + j;
      ls[row * 68 + col] = s[n][j] * scale + abias[(h * 64 + row) * 64 + col] +
                           mask[((size_t)b * 64 + row) * 64 + col];
    }
  }
  __syncthreads();

  // ---- softmax over rows: 4 lanes per row (consecutive lanes, same wave)
  {
    const int r = tid >> 2;
    const int c0 = (tid & 3) * 16;
    float e[16];
#pragma unroll
    for (int i = 0; i < 16; ++i) e[i] = ls[r * 68 + c0 + i];
    float mx = e[0];
#pragma unroll
    for (int i = 1; i < 16; ++i) mx = fmaxf(mx, e[i]);
    mx = fmaxf(mx, __shfl_xor(mx, 1));
    mx = fmaxf(mx, __shfl_xor(mx, 2));
    float sum = 0.f;
#pragma unroll
    for (int i = 0; i < 16; ++i) {
      e[i] = __expf(e[i] - mx);
      sum += e[i];
    }
    sum += __shfl_xor(sum, 1);
    sum += __shfl_xor(sum, 2);
    const float inv = 1.f / sum;
#pragma unroll
    for (int i = 0; i < 16; ++i) lp[r * 72 + c0 + i] = f2bf(e[i] * inv);
  }
  __syncthreads();

  // ---- O = P @ V : wave wid owns rows wid*16..+15; d tiles 0..1; K=64 (2 slices)
  f32x4 o[2];
  o[0] = (f32x4){0.f, 0.f, 0.f, 0.f};
  o[1] = o[0];
#pragma unroll
  for (int kk = 0; kk < 2; ++kk) {
    bf16x8 pa = *(const bf16x8*)(lp + (wid * 16 + lr) * 72 + kk * 32 + lk8);
#pragma unroll
    for (int d = 0; d < 2; ++d) {
      bf16x8 vb = *(const bf16x8*)(lvT + (d * 16 + lr) * 72 + kk * 32 + lk8);
      o[d] = __builtin_amdgcn_mfma_f32_16x16x32_bf16(pa, vb, o[d], 0, 0, 0);
    }
  }
#pragma unroll
  for (int d = 0; d < 2; ++d) {
    const int col = h * 32 + d * 16 + lr;
#pragma unroll
    for (int j = 0; j < 4; ++j) {
      const int row = sr0 + j;
      out[(size_t)(b * 64 + row) * 512 + col] = f2bf(o[d][j]);
    }
  }
}

// ---------------- launch ----------------
extern "C" void kernel_launch(void* const* d_in, const int* in_sizes, int n_in,
                              void* d_out, int out_size, void* d_ws,
                              size_t ws_size, hipStream_t stream) {
  (void)in_sizes; (void)n_in; (void)out_size; (void)ws_size;
  const float* x = (const float*)d_in[0];
  const float* abias = (const float*)d_in[1];
  const float* mask = (const float*)d_in[2];
  const float* qkv_w = (const float*)d_in[3];
  const float* qkv_b = (const float*)d_in[4];
  const float* proj_w = (const float*)d_in[5];
  const float* proj_b = (const float*)d_in[6];

  char* ws = (char*)d_ws;
  // layout (bytes):
  //   [0,           33554432)   ws_x   : x as bf16 (32768 x 512)   -- reused as attn-out
  //   [33554432,   134217728)   ws_qkv : qkv as bf16 (32768 x 1536)
  //   [134217728,  135790592)   ws_wq  : qkv_w bf16 (1536 x 512)
  //   [135790592,  136314880)   ws_wp  : proj_w bf16 (512 x 512)
  unsigned short* ws_x = (unsigned short*)(ws);
  unsigned short* ws_qkv = (unsigned short*)(ws + 33554432);
  unsigned short* ws_wq = (unsigned short*)(ws + 134217728);
  unsigned short* ws_wp = (unsigned short*)(ws + 135790592);
  unsigned short* ws_att = ws_x;  // alias: x consumed by qkv GEMM before attn writes

  f32_to_bf16_kernel<<<16384, 256, 0, stream>>>(x, ws_x, 16777216);
  f32_to_bf16_kernel<<<768, 256, 0, stream>>>(qkv_w, ws_wq, 786432);
  f32_to_bf16_kernel<<<256, 256, 0, stream>>>(proj_w, ws_wp, 262144);

  gemm_nt_kernel<true><<<dim3(256, 12), 256, 0, stream>>>(
      ws_x, ws_wq, qkv_b, ws_qkv, 32768, 1536, 512);

  attn_kernel<<<8192, 256, 0, stream>>>(ws_qkv, abias, mask, ws_att);

  gemm_nt_kernel<false><<<dim3(256, 4), 256, 0, stream>>>(
      ws_att, ws_wp, proj_b, d_out, 32768, 512, 512);
}